// Round 13
// baseline (232.125 us; speedup 1.0000x reference)
//
#include <hip/hip_runtime.h>
#include <hip/hip_fp16.h>
#include <math.h>

#define N_NODES 100000
#define N_EDGES 1250000
#define D 64
#define EPS 1e-8f

#define ZERO_BLOCKS 391     // ceil(100000/256)
#define GEMM_BLOCKS 1024
#define NODE_BLOCKS 391     // ceil(100000/256)
#define COSR_BLOCKS 4883    // ceil((N_EDGES/8)*8 / 256)
#define HALF_EDGES  625000

// ---------------------------------------------------------------------------
// Fused: cnt+ticket zeroing (blocks 0..390) + hn = normalize(tanh(xW^T+b))
// ---------------------------------------------------------------------------
__global__ __launch_bounds__(256) void k_gemm_zero(
    const float* __restrict__ x, const float* __restrict__ W,
    const float* __restrict__ b, __half* __restrict__ hn,
    int* __restrict__ cnt, int* __restrict__ ticket)
{
    if (blockIdx.x < ZERO_BLOCKS) {
        int i = blockIdx.x * 256 + threadIdx.x;
        if (i < N_NODES) cnt[i] = 0;
        if (blockIdx.x == 0 && threadIdx.x == 0) *ticket = 0;
        return;
    }
    __shared__ float xrow[4][72];
    const int lane = threadIdx.x & 63;
    const int wid  = threadIdx.x >> 6;

    float Wreg[64];
    const float4* Wv = (const float4*)(W + lane * D);
    #pragma unroll
    for (int q = 0; q < 16; ++q) {
        float4 w4 = Wv[q];
        Wreg[4*q+0] = w4.x; Wreg[4*q+1] = w4.y;
        Wreg[4*q+2] = w4.z; Wreg[4*q+3] = w4.w;
    }
    const float bj = b[lane];
    float* xl = xrow[wid];

    const int wave   = (blockIdx.x - ZERO_BLOCKS) * 4 + wid;
    const int nwaves = GEMM_BLOCKS * 4;

    for (int row = wave; row < N_NODES; row += nwaves) {
        float xv = x[(size_t)row * D + lane];
        xl[lane] = xv;
        float acc = bj;
        #pragma unroll
        for (int q = 0; q < 16; ++q) {
            float4 xk4 = *(const float4*)(xl + 4*q);
            acc = fmaf(xk4.x, Wreg[4*q+0], acc);
            acc = fmaf(xk4.y, Wreg[4*q+1], acc);
            acc = fmaf(xk4.z, Wreg[4*q+2], acc);
            acc = fmaf(xk4.w, Wreg[4*q+3], acc);
        }
        float h = tanhf(acc);
        float s = h * h;
        #pragma unroll
        for (int m = 32; m >= 1; m >>= 1) s += __shfl_xor(s, m, 64);
        float nrm = fmaxf(sqrtf(s), EPS);
        hn[(size_t)row * D + lane] = __float2half_rn(h / nrm);
    }
}

// ---------------------------------------------------------------------------
// Fused cosine + NONZERO rank. 8 lanes/EDGE-PAIR-GROUP: 8 edges/group,
// 16 row-gathers in flight per lane (2x MLP vs round-11). Only w>0 edges
// are counted (compact CSR); rank stored only for w>0 edges.
// ---------------------------------------------------------------------------
__device__ __forceinline__ float dot8h(float4 a, float4 c)
{
    const __half2* ah = (const __half2*)&a;
    const __half2* ch = (const __half2*)&c;
    float p = 0.0f;
    #pragma unroll
    for (int q = 0; q < 4; ++q) {
        float2 af = __half22float2(ah[q]);
        float2 cf = __half22float2(ch[q]);
        p = fmaf(af.x, cf.x, p);
        p = fmaf(af.y, cf.y, p);
    }
    return p;
}

__global__ __launch_bounds__(256) void k_cos_rank(
    const int* __restrict__ ei, const __half* __restrict__ hn,
    int* __restrict__ cnt, int* __restrict__ rank, float* __restrict__ wout)
{
    int t = blockIdx.x * 256 + threadIdx.x;
    int g = t >> 3, sub = t & 7;
    if (g >= N_EDGES / 8) return;
    int e0 = g * 8;
    int4 ssA = *(const int4*)(ei + e0);
    int4 ssB = *(const int4*)(ei + e0 + 4);
    int4 ddA = *(const int4*)(ei + N_EDGES + e0);
    int4 ddB = *(const int4*)(ei + N_EDGES + e0 + 4);

    float4 a0 = ((const float4*)(hn + (size_t)ssA.x * D))[sub];
    float4 c0 = ((const float4*)(hn + (size_t)ddA.x * D))[sub];
    float4 a1 = ((const float4*)(hn + (size_t)ssA.y * D))[sub];
    float4 c1 = ((const float4*)(hn + (size_t)ddA.y * D))[sub];
    float4 a2 = ((const float4*)(hn + (size_t)ssA.z * D))[sub];
    float4 c2 = ((const float4*)(hn + (size_t)ddA.z * D))[sub];
    float4 a3 = ((const float4*)(hn + (size_t)ssA.w * D))[sub];
    float4 c3 = ((const float4*)(hn + (size_t)ddA.w * D))[sub];
    float4 a4 = ((const float4*)(hn + (size_t)ssB.x * D))[sub];
    float4 c4 = ((const float4*)(hn + (size_t)ddB.x * D))[sub];
    float4 a5 = ((const float4*)(hn + (size_t)ssB.y * D))[sub];
    float4 c5 = ((const float4*)(hn + (size_t)ddB.y * D))[sub];
    float4 a6 = ((const float4*)(hn + (size_t)ssB.z * D))[sub];
    float4 c6 = ((const float4*)(hn + (size_t)ddB.z * D))[sub];
    float4 a7 = ((const float4*)(hn + (size_t)ssB.w * D))[sub];
    float4 c7 = ((const float4*)(hn + (size_t)ddB.w * D))[sub];

    float p0 = dot8h(a0, c0);
    float p1 = dot8h(a1, c1);
    float p2 = dot8h(a2, c2);
    float p3 = dot8h(a3, c3);
    float p4 = dot8h(a4, c4);
    float p5 = dot8h(a5, c5);
    float p6 = dot8h(a6, c6);
    float p7 = dot8h(a7, c7);
    #pragma unroll
    for (int m = 1; m <= 4; m <<= 1) {
        p0 += __shfl_xor(p0, m, 64);  p1 += __shfl_xor(p1, m, 64);
        p2 += __shfl_xor(p2, m, 64);  p3 += __shfl_xor(p3, m, 64);
        p4 += __shfl_xor(p4, m, 64);  p5 += __shfl_xor(p5, m, 64);
        p6 += __shfl_xor(p6, m, 64);  p7 += __shfl_xor(p7, m, 64);
    }

    float w0 = fmaxf(p0, 0.0f), w1 = fmaxf(p1, 0.0f);
    float w2 = fmaxf(p2, 0.0f), w3 = fmaxf(p3, 0.0f);
    float w4 = fmaxf(p4, 0.0f), w5 = fmaxf(p5, 0.0f);
    float w6 = fmaxf(p6, 0.0f), w7 = fmaxf(p7, 0.0f);

    if (sub == 0)
        *(float4*)(wout + e0) = make_float4(w0, w1, w2, w3);
    else if (sub == 4)
        *(float4*)(wout + e0 + 4) = make_float4(w4, w5, w6, w7);

    // each lane handles one edge's rank (static select, no dynamic indexing)
    float w = (sub == 0) ? w0 : (sub == 1) ? w1 : (sub == 2) ? w2 :
              (sub == 3) ? w3 : (sub == 4) ? w4 : (sub == 5) ? w5 :
              (sub == 6) ? w6 : w7;
    int   d = (sub == 0) ? ddA.x : (sub == 1) ? ddA.y : (sub == 2) ? ddA.z :
              (sub == 3) ? ddA.w : (sub == 4) ? ddB.x : (sub == 5) ? ddB.y :
              (sub == 6) ? ddB.z : ddB.w;
    if (w > 0.0f)
        rank[e0 + sub] = atomicAdd(cnt + d, 1);
}

// ---------------------------------------------------------------------------
// FUSED scan: per-block exclusive scan of cnt -> rowptr + bsum, then the
// LAST block (device-scope ticket) scans bsum -> boff and writes
// rowptr[N_NODES] = total nonzero edges. bsum read via atomicAdd(.,0) to
// bypass possibly-stale per-XCD L2 lines.
// ---------------------------------------------------------------------------
__device__ __forceinline__ int wave_iscan(int v, int lane)
{
    int incl = v;
    #pragma unroll
    for (int m = 1; m < 64; m <<= 1) {
        int o = __shfl_up(incl, m, 64);
        if (lane >= m) incl += o;
    }
    return incl;
}

__global__ __launch_bounds__(256) void k_scan(
    const int* __restrict__ cnt, int* __restrict__ rowptr,
    int* __restrict__ bsum, int* __restrict__ boff, int* __restrict__ ticket)
{
    __shared__ int wsum[4];
    __shared__ int amlast;
    __shared__ int btot;
    int t = threadIdx.x, b = blockIdx.x;
    int i = b * 256 + t;
    int lane = t & 63, wid = t >> 6;
    int v = (i < N_NODES) ? cnt[i] : 0;
    int incl = wave_iscan(v, lane);
    if (lane == 63) wsum[wid] = incl;
    __syncthreads();
    int off = 0;
    #pragma unroll
    for (int k = 0; k < 4; ++k) if (k < wid) off += wsum[k];
    if (i < N_NODES) rowptr[i] = off + incl - v;
    if (t == 255) bsum[b] = off + incl;
    __threadfence();                       // publish bsum device-wide
    if (t == 0) amlast = (atomicAdd(ticket, 1) == gridDim.x - 1);
    __syncthreads();
    if (!amlast) return;

    // last block: scan bsum[0..NODE_BLOCKS) -> boff, carry across chunks
    int carry = 0;
    for (int base = 0; base < NODE_BLOCKS; base += 256) {
        __syncthreads();                   // protect wsum reuse
        int ii = base + t;
        int vv = (ii < NODE_BLOCKS) ? atomicAdd(&bsum[ii], 0) : 0;  // coherent read
        int incl2 = wave_iscan(vv, lane);
        if (lane == 63) wsum[wid] = incl2;
        __syncthreads();
        int off2 = 0;
        #pragma unroll
        for (int k = 0; k < 4; ++k) if (k < wid) off2 += wsum[k];
        if (ii < NODE_BLOCKS) boff[ii] = carry + off2 + incl2 - vv;
        if (t == 255) btot = off2 + incl2;
        __syncthreads();
        carry += btot;
    }
    if (t == 0) rowptr[N_NODES] = carry;   // total NONZERO edges
}

// ---------------------------------------------------------------------------
// CSR placement, COMPACT, 2 independent edges per thread (2x MLP on the
// rowptr-gather + scatter chains).
// ---------------------------------------------------------------------------
__global__ __launch_bounds__(256) void k_place(
    const int* __restrict__ ei, const int* __restrict__ rank_pos,
    const int* __restrict__ rowptr, const int* __restrict__ boff,
    const float* __restrict__ wsrc, int2* __restrict__ pairs)
{
    int e = blockIdx.x * 256 + threadIdx.x;
    if (e >= HALF_EDGES) return;
    int e2 = e + HALF_EDGES;

    float wA = wsrc[e];
    float wB = wsrc[e2];
    int dA = ei[N_EDGES + e];
    int dB = ei[N_EDGES + e2];
    if (wA > 0.0f) {
        int pos = rowptr[dA] + boff[dA >> 8] + rank_pos[e];
        pairs[pos] = make_int2(ei[e], __float_as_int(wA));
    }
    if (wB > 0.0f) {
        int pos = rowptr[dB] + boff[dB >> 8] + rank_pos[e2];
        pairs[pos] = make_int2(ei[e2], __float_as_int(wB));
    }
}

// ---------------------------------------------------------------------------
// deg via segment-sum over COMPACT rows, 4 lanes/node x 2 slots; also emits
// rowdesc[node] = (beg, end) for the spmv passes.
// dis = rsqrt(deg+1); y0 = dis*relu(mask)
// ---------------------------------------------------------------------------
__global__ __launch_bounds__(256) void k_dis_y(
    const int* __restrict__ rowptr, const int* __restrict__ boff,
    const int2* __restrict__ pairs, const float* __restrict__ mask,
    float* __restrict__ dis, float* __restrict__ y, int2* __restrict__ rowdesc)
{
    int t = blockIdx.x * 256 + threadIdx.x;
    int node = t >> 2, l = t & 3;
    if (node >= N_NODES) return;
    int beg = rowptr[node] + boff[node >> 8];
    int np1 = node + 1;
    int end = rowptr[np1] + (np1 < N_NODES ? boff[np1 >> 8] : 0);
    float s = 0.0f;
    for (int j = beg + l; j < end; j += 8) {
        int2 p0 = pairs[j];
        int j2 = j + 4;
        int2 p1 = make_int2(0, 0);
        if (j2 < end) p1 = pairs[j2];
        s += __int_as_float(p0.y);
        s += __int_as_float(p1.y);
    }
    s += __shfl_xor(s, 1, 64);
    s += __shfl_xor(s, 2, 64);
    if (l == 0) {
        rowdesc[node] = make_int2(beg, end);
        float di = rsqrtf(fmaxf(s + 1.0f, EPS));   // +1 self-loop
        dis[node] = di;
        y[node] = di * fmaxf(mask[node], 0.0f);
    }
}

// ---------------------------------------------------------------------------
// APPNP step, 4 lanes/node x 2 slots, rowdesc single 8B read per node.
// f written only when f_out != nullptr (final step).
// ---------------------------------------------------------------------------
__global__ __launch_bounds__(256) void k_spmv(
    const int2* __restrict__ rowdesc, const int2* __restrict__ pairs,
    const float* __restrict__ y_in, const float* __restrict__ dis,
    const float* __restrict__ mask, const float* __restrict__ alpha_p,
    float* __restrict__ y_out, float* __restrict__ f_out)
{
    int t = blockIdx.x * 256 + threadIdx.x;
    int node = t >> 2, l = t & 3;
    if (node >= N_NODES) return;
    int2 rd = rowdesc[node];
    float sum = 0.0f;
    for (int j = rd.x + l; j < rd.y; j += 8) {
        int2 p0 = pairs[j];
        int j2 = j + 4;
        int2 p1 = make_int2(0, 0);
        if (j2 < rd.y) p1 = pairs[j2];
        sum += __int_as_float(p0.y) * y_in[p0.x];
        sum += __int_as_float(p1.y) * y_in[p1.x];   // p1=(0,0) adds 0*y[0]
    }
    sum += __shfl_xor(sum, 1, 64);
    sum += __shfl_xor(sum, 2, 64);
    if (l == 0) {
        float di = dis[node];
        float alpha = alpha_p[0];
        float f0 = fmaxf(mask[node], 0.0f);
        float fn = (1.0f - alpha) * di * (sum + y_in[node]) + alpha * f0;
        if (f_out) f_out[node] = fn;
        y_out[node] = di * fn;
    }
}

extern "C" void kernel_launch(void* const* d_in, const int* in_sizes, int n_in,
                              void* d_out, int out_size, void* d_ws, size_t ws_size,
                              hipStream_t stream)
{
    const float* x     = (const float*)d_in[0];
    const float* mask  = (const float*)d_in[1];
    const int*   ei    = (const int*)  d_in[2];
    const float* W     = (const float*)d_in[3];
    const float* b     = (const float*)d_in[4];
    const float* alpha = (const float*)d_in[5];

    float* out_f = (float*)d_out;
    float* out_w = (float*)d_out + N_NODES;

    // workspace layout (float-element offsets)
    float* ws = (float*)d_ws;
    __half* hn     = (__half*)ws;                  // 6.4M halves (3.2M floats)
    int2*  pairs   = (int2*) (ws + 3200000);       // <=1.25M x 8B (compact)
    int*   rank    = (int*)  (ws + 5700000);       // 1.25M
    int*   cnt     = (int*)  (ws + 6950000);       // 100k
    int*   rowptr  = (int*)  (ws + 7050000);       // 100001 (alloc 100016)
    float* dis     =          ws + 7150016;        // 100k
    float* y_a     =          ws + 7250016;        // 100k
    float* y_b     =          ws + 7350016;        // 100k
    int2*  rowdesc = (int2*) (ws + 7450016);       // 100k x 8B (200k floats)
    int*   bsum    = (int*)  (ws + 7650016);       // 391 (alloc 512)
    int*   boff    = (int*)  (ws + 7650528);       // 391 (alloc 512)
    int*   ticket  = (int*)  (ws + 7651040);       // 1

    const int placeBlocks = (HALF_EDGES + 255) / 256;                     // 2442
    const int segBlocks   = (int)(((long long)N_NODES * 4 + 255) / 256);  // 1563

    // K0: zero(cnt,ticket) + gemm_norm fused
    k_gemm_zero<<<ZERO_BLOCKS + GEMM_BLOCKS, 256, 0, stream>>>(x, W, b, hn, cnt, ticket);
    // K1: cosine + nonzero-rank fused (writes out_w, rank, cnt)
    k_cos_rank<<<COSR_BLOCKS, 256, 0, stream>>>(ei, hn, cnt, rank, out_w);
    // K2: fused rowptr scan (per-block + last-block bsum scan)
    k_scan<<<NODE_BLOCKS, 256, 0, stream>>>(cnt, rowptr, bsum, boff, ticket);
    // K3: compact CSR placement (src, w), w>0 only, 2 edges/thread
    k_place<<<placeBlocks, 256, 0, stream>>>(ei, rank, rowptr, boff, out_w, pairs);
    // K4: deg -> dis, y0, rowdesc
    k_dis_y<<<segBlocks, 256, 0, stream>>>(rowptr, boff, pairs, mask, dis, y_a, rowdesc);

    // K5..K9: 5 APPNP steps in y-domain; last writes f to d_out
    k_spmv<<<segBlocks, 256, 0, stream>>>(rowdesc, pairs, y_a, dis, mask, alpha, y_b, (float*)nullptr);
    k_spmv<<<segBlocks, 256, 0, stream>>>(rowdesc, pairs, y_b, dis, mask, alpha, y_a, (float*)nullptr);
    k_spmv<<<segBlocks, 256, 0, stream>>>(rowdesc, pairs, y_a, dis, mask, alpha, y_b, (float*)nullptr);
    k_spmv<<<segBlocks, 256, 0, stream>>>(rowdesc, pairs, y_b, dis, mask, alpha, y_a, (float*)nullptr);
    k_spmv<<<segBlocks, 256, 0, stream>>>(rowdesc, pairs, y_a, dis, mask, alpha, y_b, out_f);
}

// Round 16
// 206.371 us; speedup vs baseline: 1.1248x; 1.1248x over previous
//
#include <hip/hip_runtime.h>
#include <hip/hip_fp16.h>
#include <math.h>

#define N_NODES 100000
#define N_EDGES 1250000
#define D 64
#define EPS 1e-8f

#define ZERO_BLOCKS 391     // ceil(100000/256)
#define GEMM_BLOCKS 1024
#define NODE_BLOCKS 391     // ceil(100000/256)
#define COSR_BLOCKS 9766    // ceil((N_EDGES/4)*8 / 256)

// ---------------------------------------------------------------------------
// Fused: cnt zeroing (blocks 0..390) + hn = normalize(tanh(xW^T+b)) -> fp16
// ---------------------------------------------------------------------------
__global__ __launch_bounds__(256) void k_gemm_zero(
    const float* __restrict__ x, const float* __restrict__ W,
    const float* __restrict__ b, __half* __restrict__ hn, int* __restrict__ cnt)
{
    if (blockIdx.x < ZERO_BLOCKS) {
        int i = blockIdx.x * 256 + threadIdx.x;
        if (i < N_NODES) cnt[i] = 0;
        return;
    }
    __shared__ float xrow[4][72];
    const int lane = threadIdx.x & 63;
    const int wid  = threadIdx.x >> 6;

    float Wreg[64];
    const float4* Wv = (const float4*)(W + lane * D);
    #pragma unroll
    for (int q = 0; q < 16; ++q) {
        float4 w4 = Wv[q];
        Wreg[4*q+0] = w4.x; Wreg[4*q+1] = w4.y;
        Wreg[4*q+2] = w4.z; Wreg[4*q+3] = w4.w;
    }
    const float bj = b[lane];
    float* xl = xrow[wid];

    const int wave   = (blockIdx.x - ZERO_BLOCKS) * 4 + wid;
    const int nwaves = GEMM_BLOCKS * 4;

    for (int row = wave; row < N_NODES; row += nwaves) {
        float xv = x[(size_t)row * D + lane];
        xl[lane] = xv;
        float acc = bj;
        #pragma unroll
        for (int q = 0; q < 16; ++q) {
            float4 xk4 = *(const float4*)(xl + 4*q);
            acc = fmaf(xk4.x, Wreg[4*q+0], acc);
            acc = fmaf(xk4.y, Wreg[4*q+1], acc);
            acc = fmaf(xk4.z, Wreg[4*q+2], acc);
            acc = fmaf(xk4.w, Wreg[4*q+3], acc);
        }
        float h = tanhf(acc);
        float s = h * h;
        #pragma unroll
        for (int m = 32; m >= 1; m >>= 1) s += __shfl_xor(s, m, 64);
        float nrm = fmaxf(sqrtf(s), EPS);
        hn[(size_t)row * D + lane] = __float2half_rn(h / nrm);
    }
}

// ---------------------------------------------------------------------------
// Fused cosine + NONZERO rank. 8 lanes/edge, 4 edges/group, 8 gathers in
// flight (round-11 proven config; 8-edge variant was neutral with lower
// occupancy). Only w>0 edges are counted (compact CSR); rank stored only
// for w>0 edges.
// ---------------------------------------------------------------------------
__device__ __forceinline__ float dot8h(float4 a, float4 c)
{
    const __half2* ah = (const __half2*)&a;
    const __half2* ch = (const __half2*)&c;
    float p = 0.0f;
    #pragma unroll
    for (int q = 0; q < 4; ++q) {
        float2 af = __half22float2(ah[q]);
        float2 cf = __half22float2(ch[q]);
        p = fmaf(af.x, cf.x, p);
        p = fmaf(af.y, cf.y, p);
    }
    return p;
}

__global__ __launch_bounds__(256) void k_cos_rank(
    const int* __restrict__ ei, const __half* __restrict__ hn,
    int* __restrict__ cnt, int* __restrict__ rank, float* __restrict__ wout)
{
    int t = blockIdx.x * 256 + threadIdx.x;
    int g = t >> 3, sub = t & 7;
    if (g >= N_EDGES / 4) return;
    int e0 = g * 4;
    int4 ss = *(const int4*)(ei + e0);
    int4 dd = *(const int4*)(ei + N_EDGES + e0);

    float4 a0 = ((const float4*)(hn + (size_t)ss.x * D))[sub];
    float4 c0 = ((const float4*)(hn + (size_t)dd.x * D))[sub];
    float4 a1 = ((const float4*)(hn + (size_t)ss.y * D))[sub];
    float4 c1 = ((const float4*)(hn + (size_t)dd.y * D))[sub];
    float4 a2 = ((const float4*)(hn + (size_t)ss.z * D))[sub];
    float4 c2 = ((const float4*)(hn + (size_t)dd.z * D))[sub];
    float4 a3 = ((const float4*)(hn + (size_t)ss.w * D))[sub];
    float4 c3 = ((const float4*)(hn + (size_t)dd.w * D))[sub];

    float p0 = dot8h(a0, c0);
    float p1 = dot8h(a1, c1);
    float p2 = dot8h(a2, c2);
    float p3 = dot8h(a3, c3);
    // butterfly over the 8-lane group: ALL lanes end with the full sums
    p0 += __shfl_xor(p0, 1, 64);  p1 += __shfl_xor(p1, 1, 64);
    p2 += __shfl_xor(p2, 1, 64);  p3 += __shfl_xor(p3, 1, 64);
    p0 += __shfl_xor(p0, 2, 64);  p1 += __shfl_xor(p1, 2, 64);
    p2 += __shfl_xor(p2, 2, 64);  p3 += __shfl_xor(p3, 2, 64);
    p0 += __shfl_xor(p0, 4, 64);  p1 += __shfl_xor(p1, 4, 64);
    p2 += __shfl_xor(p2, 4, 64);  p3 += __shfl_xor(p3, 4, 64);

    float w0 = fmaxf(p0, 0.0f);
    float w1 = fmaxf(p1, 0.0f);
    float w2 = fmaxf(p2, 0.0f);
    float w3 = fmaxf(p3, 0.0f);

    if (sub == 0) {
        *(float4*)(wout + e0) = make_float4(w0, w1, w2, w3);
    }
    if (sub < 4) {
        float w = (sub == 0) ? w0 : (sub == 1) ? w1 : (sub == 2) ? w2 : w3;
        int   d = (sub == 0) ? dd.x : (sub == 1) ? dd.y : (sub == 2) ? dd.z : dd.w;
        if (w > 0.0f)
            rank[e0 + sub] = atomicAdd(cnt + d, 1);
    }
}

// ---------------------------------------------------------------------------
// Scan: exclusive prefix sum of cnt[100000] (NONZERO counts) -> rowptr
// (partial; consumers add boff[i>>8] on the fly). Two tiny kernels — the
// fused single-kernel scan with device fences regressed (round-13 lesson).
// ---------------------------------------------------------------------------
__device__ __forceinline__ int wave_iscan(int v, int lane)
{
    int incl = v;
    #pragma unroll
    for (int m = 1; m < 64; m <<= 1) {
        int o = __shfl_up(incl, m, 64);
        if (lane >= m) incl += o;
    }
    return incl;
}

__global__ __launch_bounds__(256) void k_scan1(
    const int* __restrict__ cnt, int* __restrict__ rowptr, int* __restrict__ bsum)
{
    __shared__ int wsum[4];
    int t = threadIdx.x, b = blockIdx.x;
    int i = b * 256 + t;
    int lane = t & 63, wid = t >> 6;
    int v = (i < N_NODES) ? cnt[i] : 0;
    int incl = wave_iscan(v, lane);
    if (lane == 63) wsum[wid] = incl;
    __syncthreads();
    int off = 0;
    #pragma unroll
    for (int k = 0; k < 4; ++k) if (k < wid) off += wsum[k];
    if (i < N_NODES) rowptr[i] = off + incl - v;
    if (t == 255) bsum[b] = off + incl;
}

__global__ __launch_bounds__(512) void k_scan2(
    const int* __restrict__ bsum, int* __restrict__ boff, int nblk,
    int* __restrict__ rowptr)
{
    __shared__ int wsum[8];
    int t = threadIdx.x;
    int lane = t & 63, wid = t >> 6;
    int v = (t < nblk) ? bsum[t] : 0;
    int incl = wave_iscan(v, lane);
    if (lane == 63) wsum[wid] = incl;
    __syncthreads();
    int off = 0;
    #pragma unroll
    for (int k = 0; k < 8; ++k) if (k < wid) off += wsum[k];
    if (t < nblk) boff[t] = off + incl - v;
    if (t == nblk - 1) rowptr[N_NODES] = off + incl;   // total NONZERO edges
}

// ---------------------------------------------------------------------------
// CSR placement, COMPACT: only w>0 edges get a slot.
// ---------------------------------------------------------------------------
__global__ __launch_bounds__(256) void k_place(
    const int* __restrict__ ei, const int* __restrict__ rank_pos,
    const int* __restrict__ rowptr, const int* __restrict__ boff,
    const float* __restrict__ wsrc, int2* __restrict__ pairs)
{
    int e = blockIdx.x * 256 + threadIdx.x;
    if (e >= N_EDGES) return;
    float w = wsrc[e];
    if (!(w > 0.0f)) return;
    int s = ei[e];
    int d = ei[N_EDGES + e];
    int pos = rowptr[d] + boff[d >> 8] + rank_pos[e];
    pairs[pos] = make_int2(s, __float_as_int(w));
}

// ---------------------------------------------------------------------------
// deg via segment-sum over COMPACT rows, 4 lanes/node x 2 slots; also emits
// rowdesc[node] = (beg, end) so spmv does one 8B row read.
// dis = rsqrt(deg+1); y0 = dis*relu(mask)
// ---------------------------------------------------------------------------
__global__ __launch_bounds__(256) void k_dis_y(
    const int* __restrict__ rowptr, const int* __restrict__ boff,
    const int2* __restrict__ pairs, const float* __restrict__ mask,
    float* __restrict__ dis, float* __restrict__ y, int2* __restrict__ rowdesc)
{
    int t = blockIdx.x * 256 + threadIdx.x;
    int node = t >> 2, l = t & 3;
    if (node >= N_NODES) return;
    int beg = rowptr[node] + boff[node >> 8];
    int np1 = node + 1;
    int end = rowptr[np1] + (np1 < N_NODES ? boff[np1 >> 8] : 0);
    float s = 0.0f;
    for (int j = beg + l; j < end; j += 8) {
        int2 p0 = pairs[j];
        int j2 = j + 4;
        int2 p1 = make_int2(0, 0);
        if (j2 < end) p1 = pairs[j2];
        s += __int_as_float(p0.y);
        s += __int_as_float(p1.y);
    }
    s += __shfl_xor(s, 1, 64);
    s += __shfl_xor(s, 2, 64);
    if (l == 0) {
        rowdesc[node] = make_int2(beg, end);
        float di = rsqrtf(fmaxf(s + 1.0f, EPS));   // +1 self-loop
        dis[node] = di;
        y[node] = di * fmaxf(mask[node], 0.0f);
    }
}

// ---------------------------------------------------------------------------
// APPNP step, 4 lanes/node x 2 slots, rowdesc single 8B read per node.
// f written only when f_out != nullptr (final step).
// ---------------------------------------------------------------------------
__global__ __launch_bounds__(256) void k_spmv(
    const int2* __restrict__ rowdesc, const int2* __restrict__ pairs,
    const float* __restrict__ y_in, const float* __restrict__ dis,
    const float* __restrict__ mask, const float* __restrict__ alpha_p,
    float* __restrict__ y_out, float* __restrict__ f_out)
{
    int t = blockIdx.x * 256 + threadIdx.x;
    int node = t >> 2, l = t & 3;
    if (node >= N_NODES) return;
    int2 rd = rowdesc[node];
    float sum = 0.0f;
    for (int j = rd.x + l; j < rd.y; j += 8) {
        int2 p0 = pairs[j];
        int j2 = j + 4;
        int2 p1 = make_int2(0, 0);
        if (j2 < rd.y) p1 = pairs[j2];
        sum += __int_as_float(p0.y) * y_in[p0.x];
        sum += __int_as_float(p1.y) * y_in[p1.x];   // p1=(0,0) adds 0*y[0]
    }
    sum += __shfl_xor(sum, 1, 64);
    sum += __shfl_xor(sum, 2, 64);
    if (l == 0) {
        float di = dis[node];
        float alpha = alpha_p[0];
        float f0 = fmaxf(mask[node], 0.0f);
        float fn = (1.0f - alpha) * di * (sum + y_in[node]) + alpha * f0;
        if (f_out) f_out[node] = fn;
        y_out[node] = di * fn;
    }
}

extern "C" void kernel_launch(void* const* d_in, const int* in_sizes, int n_in,
                              void* d_out, int out_size, void* d_ws, size_t ws_size,
                              hipStream_t stream)
{
    const float* x     = (const float*)d_in[0];
    const float* mask  = (const float*)d_in[1];
    const int*   ei    = (const int*)  d_in[2];
    const float* W     = (const float*)d_in[3];
    const float* b     = (const float*)d_in[4];
    const float* alpha = (const float*)d_in[5];

    float* out_f = (float*)d_out;
    float* out_w = (float*)d_out + N_NODES;

    // workspace layout (float-element offsets)
    float* ws = (float*)d_ws;
    __half* hn     = (__half*)ws;                  // 6.4M halves (3.2M floats)
    int2*  pairs   = (int2*) (ws + 3200000);       // <=1.25M x 8B (compact)
    int*   rank    = (int*)  (ws + 5700000);       // 1.25M
    int*   cnt     = (int*)  (ws + 6950000);       // 100k
    int*   rowptr  = (int*)  (ws + 7050000);       // 100001 (alloc 100016)
    float* dis     =          ws + 7150016;        // 100k
    float* y_a     =          ws + 7250016;        // 100k
    float* y_b     =          ws + 7350016;        // 100k
    int2*  rowdesc = (int2*) (ws + 7450016);       // 100k x 8B (200k floats)
    int*   bsum    = (int*)  (ws + 7650016);       // 391 (alloc 512)
    int*   boff    = (int*)  (ws + 7650528);       // 391

    const int edgeBlocks = (N_EDGES + 255) / 256;                         // 4883
    const int segBlocks  = (int)(((long long)N_NODES * 4 + 255) / 256);   // 1563

    // K0: zero(cnt) + gemm_norm fused
    k_gemm_zero<<<ZERO_BLOCKS + GEMM_BLOCKS, 256, 0, stream>>>(x, W, b, hn, cnt);
    // K1: cosine + nonzero-rank fused (writes out_w, rank, cnt)
    k_cos_rank<<<COSR_BLOCKS, 256, 0, stream>>>(ei, hn, cnt, rank, out_w);
    // K2..K3: rowptr scan (partial rowptr + boff; consumers fold boff on the fly)
    k_scan1<<<NODE_BLOCKS, 256, 0, stream>>>(cnt, rowptr, bsum);
    k_scan2<<<1, 512, 0, stream>>>(bsum, boff, NODE_BLOCKS, rowptr);
    // K4: compact CSR placement (src, w), w>0 only
    k_place<<<edgeBlocks, 256, 0, stream>>>(ei, rank, rowptr, boff, out_w, pairs);
    // K5: deg -> dis, y0, rowdesc
    k_dis_y<<<segBlocks, 256, 0, stream>>>(rowptr, boff, pairs, mask, dis, y_a, rowdesc);

    // K6..K10: 5 APPNP steps in y-domain; last writes f to d_out
    k_spmv<<<segBlocks, 256, 0, stream>>>(rowdesc, pairs, y_a, dis, mask, alpha, y_b, (float*)nullptr);
    k_spmv<<<segBlocks, 256, 0, stream>>>(rowdesc, pairs, y_b, dis, mask, alpha, y_a, (float*)nullptr);
    k_spmv<<<segBlocks, 256, 0, stream>>>(rowdesc, pairs, y_a, dis, mask, alpha, y_b, (float*)nullptr);
    k_spmv<<<segBlocks, 256, 0, stream>>>(rowdesc, pairs, y_b, dis, mask, alpha, y_a, (float*)nullptr);
    k_spmv<<<segBlocks, 256, 0, stream>>>(rowdesc, pairs, y_a, dis, mask, alpha, y_b, out_f);
}

// Round 17
// 202.842 us; speedup vs baseline: 1.1444x; 1.0174x over previous
//
#include <hip/hip_runtime.h>
#include <hip/hip_fp16.h>
#include <math.h>

#define N_NODES 100000
#define N_EDGES 1250000
#define D 64
#define EPS 1e-8f

#define ZERO_BLOCKS 391     // ceil(100000/256)
#define GEMM_BLOCKS 1024
#define NODE_BLOCKS 391     // ceil(100000/256)
#define COSR_BLOCKS 9766    // ceil((N_EDGES/4)*8 / 256)

// ---------------------------------------------------------------------------
// Fused: cnt64 zeroing (blocks 0..390) + hn = normalize(tanh(xW^T+b)) -> fp16
// ---------------------------------------------------------------------------
__global__ __launch_bounds__(256) void k_gemm_zero(
    const float* __restrict__ x, const float* __restrict__ W,
    const float* __restrict__ b, __half* __restrict__ hn,
    unsigned long long* __restrict__ cnt64)
{
    if (blockIdx.x < ZERO_BLOCKS) {
        int i = blockIdx.x * 256 + threadIdx.x;
        if (i < N_NODES) cnt64[i] = 0ULL;
        return;
    }
    __shared__ float xrow[4][72];
    const int lane = threadIdx.x & 63;
    const int wid  = threadIdx.x >> 6;

    float Wreg[64];
    const float4* Wv = (const float4*)(W + lane * D);
    #pragma unroll
    for (int q = 0; q < 16; ++q) {
        float4 w4 = Wv[q];
        Wreg[4*q+0] = w4.x; Wreg[4*q+1] = w4.y;
        Wreg[4*q+2] = w4.z; Wreg[4*q+3] = w4.w;
    }
    const float bj = b[lane];
    float* xl = xrow[wid];

    const int wave   = (blockIdx.x - ZERO_BLOCKS) * 4 + wid;
    const int nwaves = GEMM_BLOCKS * 4;

    for (int row = wave; row < N_NODES; row += nwaves) {
        float xv = x[(size_t)row * D + lane];
        xl[lane] = xv;
        float acc = bj;
        #pragma unroll
        for (int q = 0; q < 16; ++q) {
            float4 xk4 = *(const float4*)(xl + 4*q);
            acc = fmaf(xk4.x, Wreg[4*q+0], acc);
            acc = fmaf(xk4.y, Wreg[4*q+1], acc);
            acc = fmaf(xk4.z, Wreg[4*q+2], acc);
            acc = fmaf(xk4.w, Wreg[4*q+3], acc);
        }
        float h = tanhf(acc);
        float s = h * h;
        #pragma unroll
        for (int m = 32; m >= 1; m >>= 1) s += __shfl_xor(s, m, 64);
        float nrm = fmaxf(sqrtf(s), EPS);
        hn[(size_t)row * D + lane] = __float2half_rn(h / nrm);
    }
}

// ---------------------------------------------------------------------------
// Fused cosine + NONZERO rank + deg-sum, all in ONE packed 64-bit atomic:
//   cnt64[d] += (1<<40) | (ull)(w * 2^32)
// high 24 bits: nonzero-edge count (old>>40 = this edge's rank)
// low 40 bits: sum of w in 2^-32 fixed point (max deg ~40 -> < 2^38, safe)
// This removes the separate dis_y pairs-pass entirely.
// 8 lanes/edge, 4 edges/group, 8 gathers in flight (proven config).
// ---------------------------------------------------------------------------
__device__ __forceinline__ float dot8h(float4 a, float4 c)
{
    const __half2* ah = (const __half2*)&a;
    const __half2* ch = (const __half2*)&c;
    float p = 0.0f;
    #pragma unroll
    for (int q = 0; q < 4; ++q) {
        float2 af = __half22float2(ah[q]);
        float2 cf = __half22float2(ch[q]);
        p = fmaf(af.x, cf.x, p);
        p = fmaf(af.y, cf.y, p);
    }
    return p;
}

__global__ __launch_bounds__(256) void k_cos_rank(
    const int* __restrict__ ei, const __half* __restrict__ hn,
    unsigned long long* __restrict__ cnt64, int* __restrict__ rank,
    float* __restrict__ wout)
{
    int t = blockIdx.x * 256 + threadIdx.x;
    int g = t >> 3, sub = t & 7;
    if (g >= N_EDGES / 4) return;
    int e0 = g * 4;
    int4 ss = *(const int4*)(ei + e0);
    int4 dd = *(const int4*)(ei + N_EDGES + e0);

    float4 a0 = ((const float4*)(hn + (size_t)ss.x * D))[sub];
    float4 c0 = ((const float4*)(hn + (size_t)dd.x * D))[sub];
    float4 a1 = ((const float4*)(hn + (size_t)ss.y * D))[sub];
    float4 c1 = ((const float4*)(hn + (size_t)dd.y * D))[sub];
    float4 a2 = ((const float4*)(hn + (size_t)ss.z * D))[sub];
    float4 c2 = ((const float4*)(hn + (size_t)dd.z * D))[sub];
    float4 a3 = ((const float4*)(hn + (size_t)ss.w * D))[sub];
    float4 c3 = ((const float4*)(hn + (size_t)dd.w * D))[sub];

    float p0 = dot8h(a0, c0);
    float p1 = dot8h(a1, c1);
    float p2 = dot8h(a2, c2);
    float p3 = dot8h(a3, c3);
    // butterfly over the 8-lane group: ALL lanes end with the full sums
    p0 += __shfl_xor(p0, 1, 64);  p1 += __shfl_xor(p1, 1, 64);
    p2 += __shfl_xor(p2, 1, 64);  p3 += __shfl_xor(p3, 1, 64);
    p0 += __shfl_xor(p0, 2, 64);  p1 += __shfl_xor(p1, 2, 64);
    p2 += __shfl_xor(p2, 2, 64);  p3 += __shfl_xor(p3, 2, 64);
    p0 += __shfl_xor(p0, 4, 64);  p1 += __shfl_xor(p1, 4, 64);
    p2 += __shfl_xor(p2, 4, 64);  p3 += __shfl_xor(p3, 4, 64);

    float w0 = fmaxf(p0, 0.0f);
    float w1 = fmaxf(p1, 0.0f);
    float w2 = fmaxf(p2, 0.0f);
    float w3 = fmaxf(p3, 0.0f);

    if (sub == 0) {
        *(float4*)(wout + e0) = make_float4(w0, w1, w2, w3);
    }
    if (sub < 4) {
        float w = (sub == 0) ? w0 : (sub == 1) ? w1 : (sub == 2) ? w2 : w3;
        int   d = (sub == 0) ? dd.x : (sub == 1) ? dd.y : (sub == 2) ? dd.z : dd.w;
        if (w > 0.0f) {
            unsigned long long pack =
                (1ULL << 40) | (unsigned long long)(w * 4294967296.0f);
            unsigned long long old = atomicAdd(cnt64 + d, pack);
            rank[e0 + sub] = (int)(old >> 40);
        }
    }
}

// ---------------------------------------------------------------------------
// Scan + fused dis/y0: per-node load cnt64 once; count (high bits) feeds the
// rowptr scan; w-sum (low bits) yields dis = rsqrt(deg+1) and y0 elementwise.
// rowptr partial; consumers add boff[i>>8] on the fly.
// ---------------------------------------------------------------------------
__device__ __forceinline__ int wave_iscan(int v, int lane)
{
    int incl = v;
    #pragma unroll
    for (int m = 1; m < 64; m <<= 1) {
        int o = __shfl_up(incl, m, 64);
        if (lane >= m) incl += o;
    }
    return incl;
}

__global__ __launch_bounds__(256) void k_scan1(
    const unsigned long long* __restrict__ cnt64, int* __restrict__ rowptr,
    int* __restrict__ bsum, const float* __restrict__ mask,
    float* __restrict__ dis, float* __restrict__ y)
{
    __shared__ int wsum[4];
    int t = threadIdx.x, b = blockIdx.x;
    int i = b * 256 + t;
    int lane = t & 63, wid = t >> 6;
    unsigned long long pv = (i < N_NODES) ? cnt64[i] : 0ULL;
    int v = (int)(pv >> 40);
    if (i < N_NODES) {
        float degsum = (float)(pv & 0xFFFFFFFFFFULL) * 2.3283064365386963e-10f; // *2^-32
        float di = rsqrtf(fmaxf(degsum + 1.0f, EPS));   // +1 self-loop
        dis[i] = di;
        y[i] = di * fmaxf(mask[i], 0.0f);
    }
    int incl = wave_iscan(v, lane);
    if (lane == 63) wsum[wid] = incl;
    __syncthreads();
    int off = 0;
    #pragma unroll
    for (int k = 0; k < 4; ++k) if (k < wid) off += wsum[k];
    if (i < N_NODES) rowptr[i] = off + incl - v;
    if (t == 255) bsum[b] = off + incl;
}

__global__ __launch_bounds__(512) void k_scan2(
    const int* __restrict__ bsum, int* __restrict__ boff, int nblk,
    int* __restrict__ rowptr)
{
    __shared__ int wsum[8];
    int t = threadIdx.x;
    int lane = t & 63, wid = t >> 6;
    int v = (t < nblk) ? bsum[t] : 0;
    int incl = wave_iscan(v, lane);
    if (lane == 63) wsum[wid] = incl;
    __syncthreads();
    int off = 0;
    #pragma unroll
    for (int k = 0; k < 8; ++k) if (k < wid) off += wsum[k];
    if (t < nblk) boff[t] = off + incl - v;
    if (t == nblk - 1) rowptr[N_NODES] = off + incl;   // total NONZERO edges
}

// ---------------------------------------------------------------------------
// CSR placement, COMPACT: only w>0 edges get a slot.
// ---------------------------------------------------------------------------
__global__ __launch_bounds__(256) void k_place(
    const int* __restrict__ ei, const int* __restrict__ rank_pos,
    const int* __restrict__ rowptr, const int* __restrict__ boff,
    const float* __restrict__ wsrc, int2* __restrict__ pairs)
{
    int e = blockIdx.x * 256 + threadIdx.x;
    if (e >= N_EDGES) return;
    float w = wsrc[e];
    if (!(w > 0.0f)) return;
    int s = ei[e];
    int d = ei[N_EDGES + e];
    int pos = rowptr[d] + boff[d >> 8] + rank_pos[e];
    pairs[pos] = make_int2(s, __float_as_int(w));
}

// ---------------------------------------------------------------------------
// APPNP step, 4 lanes/node x 2 slots (proven round-11 config):
// f'_i = (1-a) * dis_i * ( sum_j w_ij*y_j + y_i ) + a*relu(mask_i)
// y'_i = dis_i * f'_i ;  f written only on the final step.
// ---------------------------------------------------------------------------
__global__ __launch_bounds__(256) void k_spmv(
    const int* __restrict__ rowptr, const int* __restrict__ boff,
    const int2* __restrict__ pairs,
    const float* __restrict__ y_in, const float* __restrict__ dis,
    const float* __restrict__ mask, const float* __restrict__ alpha_p,
    float* __restrict__ y_out, float* __restrict__ f_out)
{
    int t = blockIdx.x * 256 + threadIdx.x;
    int node = t >> 2, l = t & 3;
    if (node >= N_NODES) return;
    int beg = rowptr[node] + boff[node >> 8];
    int np1 = node + 1;
    int end = rowptr[np1] + (np1 < N_NODES ? boff[np1 >> 8] : 0);
    float sum = 0.0f;
    for (int j = beg + l; j < end; j += 8) {
        int2 p0 = pairs[j];
        int j2 = j + 4;
        int2 p1 = make_int2(0, 0);
        if (j2 < end) p1 = pairs[j2];
        sum += __int_as_float(p0.y) * y_in[p0.x];
        sum += __int_as_float(p1.y) * y_in[p1.x];   // p1=(0,0) adds 0*y[0]
    }
    sum += __shfl_xor(sum, 1, 64);
    sum += __shfl_xor(sum, 2, 64);
    if (l == 0) {
        float di = dis[node];
        float alpha = alpha_p[0];
        float f0 = fmaxf(mask[node], 0.0f);
        float fn = (1.0f - alpha) * di * (sum + y_in[node]) + alpha * f0;
        if (f_out) f_out[node] = fn;
        y_out[node] = di * fn;
    }
}

extern "C" void kernel_launch(void* const* d_in, const int* in_sizes, int n_in,
                              void* d_out, int out_size, void* d_ws, size_t ws_size,
                              hipStream_t stream)
{
    const float* x     = (const float*)d_in[0];
    const float* mask  = (const float*)d_in[1];
    const int*   ei    = (const int*)  d_in[2];
    const float* W     = (const float*)d_in[3];
    const float* b     = (const float*)d_in[4];
    const float* alpha = (const float*)d_in[5];

    float* out_f = (float*)d_out;
    float* out_w = (float*)d_out + N_NODES;

    // workspace layout (float-element offsets)
    float* ws = (float*)d_ws;
    __half* hn    = (__half*)ws;                           // 6.4M halves
    int2*  pairs  = (int2*) (ws + 3200000);                // <=1.25M x 8B (compact)
    int*   rank   = (int*)  (ws + 5700000);                // 1.25M
    unsigned long long* cnt64 = (unsigned long long*)(ws + 6950000);  // 100k x 8B
    int*   rowptr = (int*)  (ws + 7150000);                // 100001 (alloc 100016)
    float* dis    =          ws + 7250016;                 // 100k
    float* y_a    =          ws + 7350016;                 // 100k
    float* y_b    =          ws + 7450016;                 // 100k
    int*   bsum   = (int*)  (ws + 7550016);                // 391 (alloc 512)
    int*   boff   = (int*)  (ws + 7550528);                // 391

    const int edgeBlocks = (N_EDGES + 255) / 256;                         // 4883
    const int segBlocks  = (int)(((long long)N_NODES * 4 + 255) / 256);   // 1563

    // K0: zero(cnt64) + gemm_norm fused
    k_gemm_zero<<<ZERO_BLOCKS + GEMM_BLOCKS, 256, 0, stream>>>(x, W, b, hn, cnt64);
    // K1: cosine + packed rank/deg atomic (writes out_w, rank, cnt64)
    k_cos_rank<<<COSR_BLOCKS, 256, 0, stream>>>(ei, hn, cnt64, rank, out_w);
    // K2: rowptr scan + fused elementwise dis/y0 (from cnt64 low bits)
    k_scan1<<<NODE_BLOCKS, 256, 0, stream>>>(cnt64, rowptr, bsum, mask, dis, y_a);
    // K3: block-offset scan
    k_scan2<<<1, 512, 0, stream>>>(bsum, boff, NODE_BLOCKS, rowptr);
    // K4: compact CSR placement (src, w), w>0 only
    k_place<<<edgeBlocks, 256, 0, stream>>>(ei, rank, rowptr, boff, out_w, pairs);

    // K5..K9: 5 APPNP steps in y-domain; last writes f to d_out
    k_spmv<<<segBlocks, 256, 0, stream>>>(rowptr, boff, pairs, y_a, dis, mask, alpha, y_b, (float*)nullptr);
    k_spmv<<<segBlocks, 256, 0, stream>>>(rowptr, boff, pairs, y_b, dis, mask, alpha, y_a, (float*)nullptr);
    k_spmv<<<segBlocks, 256, 0, stream>>>(rowptr, boff, pairs, y_a, dis, mask, alpha, y_b, (float*)nullptr);
    k_spmv<<<segBlocks, 256, 0, stream>>>(rowptr, boff, pairs, y_b, dis, mask, alpha, y_a, (float*)nullptr);
    k_spmv<<<segBlocks, 256, 0, stream>>>(rowptr, boff, pairs, y_a, dis, mask, alpha, y_b, out_f);
}

// Round 18
// 202.240 us; speedup vs baseline: 1.1478x; 1.0030x over previous
//
#include <hip/hip_runtime.h>
#include <hip/hip_fp16.h>
#include <math.h>

#define N_NODES 100000
#define N_EDGES 1250000
#define D 64
#define EPS 1e-8f

#define ZERO_BLOCKS 391     // ceil(100000/256)
#define GEMM_BLOCKS 1024
#define NODE_BLOCKS 391     // ceil(100000/256)
#define COSR_BLOCKS 9766    // ceil((N_EDGES/4)*8 / 256)

// ---------------------------------------------------------------------------
// Fused: cnt64 zeroing (blocks 0..390) + hn = normalize(tanh(xW^T+b)) -> fp16
// ---------------------------------------------------------------------------
__global__ __launch_bounds__(256) void k_gemm_zero(
    const float* __restrict__ x, const float* __restrict__ W,
    const float* __restrict__ b, __half* __restrict__ hn,
    unsigned long long* __restrict__ cnt64)
{
    if (blockIdx.x < ZERO_BLOCKS) {
        int i = blockIdx.x * 256 + threadIdx.x;
        if (i < N_NODES) cnt64[i] = 0ULL;
        return;
    }
    __shared__ float xrow[4][72];
    const int lane = threadIdx.x & 63;
    const int wid  = threadIdx.x >> 6;

    float Wreg[64];
    const float4* Wv = (const float4*)(W + lane * D);
    #pragma unroll
    for (int q = 0; q < 16; ++q) {
        float4 w4 = Wv[q];
        Wreg[4*q+0] = w4.x; Wreg[4*q+1] = w4.y;
        Wreg[4*q+2] = w4.z; Wreg[4*q+3] = w4.w;
    }
    const float bj = b[lane];
    float* xl = xrow[wid];

    const int wave   = (blockIdx.x - ZERO_BLOCKS) * 4 + wid;
    const int nwaves = GEMM_BLOCKS * 4;

    for (int row = wave; row < N_NODES; row += nwaves) {
        float xv = x[(size_t)row * D + lane];
        xl[lane] = xv;
        float acc = bj;
        #pragma unroll
        for (int q = 0; q < 16; ++q) {
            float4 xk4 = *(const float4*)(xl + 4*q);
            acc = fmaf(xk4.x, Wreg[4*q+0], acc);
            acc = fmaf(xk4.y, Wreg[4*q+1], acc);
            acc = fmaf(xk4.z, Wreg[4*q+2], acc);
            acc = fmaf(xk4.w, Wreg[4*q+3], acc);
        }
        float h = tanhf(acc);
        float s = h * h;
        #pragma unroll
        for (int m = 32; m >= 1; m >>= 1) s += __shfl_xor(s, m, 64);
        float nrm = fmaxf(sqrtf(s), EPS);
        hn[(size_t)row * D + lane] = __float2half_rn(h / nrm);
    }
}

// ---------------------------------------------------------------------------
// Fused cosine + NONZERO rank + deg-sum via ONE packed 64-bit atomic:
//   cnt64[d] += (1<<40) | (ull)(w * 2^32)
// rank stored as UCHAR (max nonzero in-degree ~35 << 255) -> 1/4 the bytes.
// 8 lanes/edge, 4 edges/group, 8 gathers in flight (proven config).
// ---------------------------------------------------------------------------
__device__ __forceinline__ float dot8h(float4 a, float4 c)
{
    const __half2* ah = (const __half2*)&a;
    const __half2* ch = (const __half2*)&c;
    float p = 0.0f;
    #pragma unroll
    for (int q = 0; q < 4; ++q) {
        float2 af = __half22float2(ah[q]);
        float2 cf = __half22float2(ch[q]);
        p = fmaf(af.x, cf.x, p);
        p = fmaf(af.y, cf.y, p);
    }
    return p;
}

__global__ __launch_bounds__(256) void k_cos_rank(
    const int* __restrict__ ei, const __half* __restrict__ hn,
    unsigned long long* __restrict__ cnt64, unsigned char* __restrict__ rank,
    float* __restrict__ wout)
{
    int t = blockIdx.x * 256 + threadIdx.x;
    int g = t >> 3, sub = t & 7;
    if (g >= N_EDGES / 4) return;
    int e0 = g * 4;
    int4 ss = *(const int4*)(ei + e0);
    int4 dd = *(const int4*)(ei + N_EDGES + e0);

    float4 a0 = ((const float4*)(hn + (size_t)ss.x * D))[sub];
    float4 c0 = ((const float4*)(hn + (size_t)dd.x * D))[sub];
    float4 a1 = ((const float4*)(hn + (size_t)ss.y * D))[sub];
    float4 c1 = ((const float4*)(hn + (size_t)dd.y * D))[sub];
    float4 a2 = ((const float4*)(hn + (size_t)ss.z * D))[sub];
    float4 c2 = ((const float4*)(hn + (size_t)dd.z * D))[sub];
    float4 a3 = ((const float4*)(hn + (size_t)ss.w * D))[sub];
    float4 c3 = ((const float4*)(hn + (size_t)dd.w * D))[sub];

    float p0 = dot8h(a0, c0);
    float p1 = dot8h(a1, c1);
    float p2 = dot8h(a2, c2);
    float p3 = dot8h(a3, c3);
    // butterfly over the 8-lane group: ALL lanes end with the full sums
    p0 += __shfl_xor(p0, 1, 64);  p1 += __shfl_xor(p1, 1, 64);
    p2 += __shfl_xor(p2, 1, 64);  p3 += __shfl_xor(p3, 1, 64);
    p0 += __shfl_xor(p0, 2, 64);  p1 += __shfl_xor(p1, 2, 64);
    p2 += __shfl_xor(p2, 2, 64);  p3 += __shfl_xor(p3, 2, 64);
    p0 += __shfl_xor(p0, 4, 64);  p1 += __shfl_xor(p1, 4, 64);
    p2 += __shfl_xor(p2, 4, 64);  p3 += __shfl_xor(p3, 4, 64);

    float w0 = fmaxf(p0, 0.0f);
    float w1 = fmaxf(p1, 0.0f);
    float w2 = fmaxf(p2, 0.0f);
    float w3 = fmaxf(p3, 0.0f);

    if (sub == 0) {
        *(float4*)(wout + e0) = make_float4(w0, w1, w2, w3);
    }
    if (sub < 4) {
        float w = (sub == 0) ? w0 : (sub == 1) ? w1 : (sub == 2) ? w2 : w3;
        int   d = (sub == 0) ? dd.x : (sub == 1) ? dd.y : (sub == 2) ? dd.z : dd.w;
        if (w > 0.0f) {
            unsigned long long pack =
                (1ULL << 40) | (unsigned long long)(w * 4294967296.0f);
            unsigned long long old = atomicAdd(cnt64 + d, pack);
            rank[e0 + sub] = (unsigned char)(old >> 40);
        }
    }
}

// ---------------------------------------------------------------------------
// Scan + fused per-node constants: count (high bits of cnt64) feeds the
// rowptr scan; w-sum (low bits) yields dis, y0, and the folded APPNP coefs
//   A = (1-alpha)*dis^2 ,  B = alpha*dis*relu(mask)
// so fast spmv passes are y' = A*(sum+y) + B.
// ---------------------------------------------------------------------------
__device__ __forceinline__ int wave_iscan(int v, int lane)
{
    int incl = v;
    #pragma unroll
    for (int m = 1; m < 64; m <<= 1) {
        int o = __shfl_up(incl, m, 64);
        if (lane >= m) incl += o;
    }
    return incl;
}

__global__ __launch_bounds__(256) void k_scan1(
    const unsigned long long* __restrict__ cnt64, int* __restrict__ rowptr,
    int* __restrict__ bsum, const float* __restrict__ mask,
    const float* __restrict__ alpha_p, float* __restrict__ dis,
    float* __restrict__ y, float* __restrict__ Ac, float* __restrict__ Bc)
{
    __shared__ int wsum[4];
    int t = threadIdx.x, b = blockIdx.x;
    int i = b * 256 + t;
    int lane = t & 63, wid = t >> 6;
    unsigned long long pv = (i < N_NODES) ? cnt64[i] : 0ULL;
    int v = (int)(pv >> 40);
    if (i < N_NODES) {
        float degsum = (float)(pv & 0xFFFFFFFFFFULL) * 2.3283064365386963e-10f; // *2^-32
        float di = rsqrtf(fmaxf(degsum + 1.0f, EPS));   // +1 self-loop
        float al = alpha_p[0];
        float m0 = fmaxf(mask[i], 0.0f);
        dis[i] = di;
        y[i]   = di * m0;
        Ac[i]  = (1.0f - al) * di * di;
        Bc[i]  = al * di * m0;
    }
    int incl = wave_iscan(v, lane);
    if (lane == 63) wsum[wid] = incl;
    __syncthreads();
    int off = 0;
    #pragma unroll
    for (int k = 0; k < 4; ++k) if (k < wid) off += wsum[k];
    if (i < N_NODES) rowptr[i] = off + incl - v;
    if (t == 255) bsum[b] = off + incl;
}

__global__ __launch_bounds__(512) void k_scan2(
    const int* __restrict__ bsum, int* __restrict__ boff, int nblk,
    int* __restrict__ rowptr)
{
    __shared__ int wsum[8];
    int t = threadIdx.x;
    int lane = t & 63, wid = t >> 6;
    int v = (t < nblk) ? bsum[t] : 0;
    int incl = wave_iscan(v, lane);
    if (lane == 63) wsum[wid] = incl;
    __syncthreads();
    int off = 0;
    #pragma unroll
    for (int k = 0; k < 8; ++k) if (k < wid) off += wsum[k];
    if (t < nblk) boff[t] = off + incl - v;
    if (t == nblk - 1) rowptr[N_NODES] = off + incl;   // total NONZERO edges
}

// ---------------------------------------------------------------------------
// CSR placement, COMPACT + PACKED: pairs[pos] = (src<<15) | w_q15.
// src < 2^17, w in [0,1] as 15-bit fixed point (quant err 1.5e-5 << 2^-7).
// ---------------------------------------------------------------------------
__global__ __launch_bounds__(256) void k_place(
    const int* __restrict__ ei, const unsigned char* __restrict__ rank_pos,
    const int* __restrict__ rowptr, const int* __restrict__ boff,
    const float* __restrict__ wsrc, unsigned int* __restrict__ pairs)
{
    int e = blockIdx.x * 256 + threadIdx.x;
    if (e >= N_EDGES) return;
    float w = wsrc[e];
    if (!(w > 0.0f)) return;
    int s = ei[e];
    int d = ei[N_EDGES + e];
    int pos = rowptr[d] + boff[d >> 8] + (int)rank_pos[e];
    unsigned int wq = (unsigned int)(w * 32767.0f + 0.5f);
    if (wq > 32767u) wq = 32767u;
    pairs[pos] = ((unsigned int)s << 15) | wq;
}

// ---------------------------------------------------------------------------
// FAST APPNP step: y'_i = A_i*(sum_j w_ij y_j + y_i) + B_i.
// 4 lanes/node x 2 slots (proven config), packed 4B pairs.
// ---------------------------------------------------------------------------
__global__ __launch_bounds__(256) void k_spmv_fast(
    const int* __restrict__ rowptr, const int* __restrict__ boff,
    const unsigned int* __restrict__ pairs,
    const float* __restrict__ y_in, const float* __restrict__ Ac,
    const float* __restrict__ Bc, float* __restrict__ y_out)
{
    int t = blockIdx.x * 256 + threadIdx.x;
    int node = t >> 2, l = t & 3;
    if (node >= N_NODES) return;
    int beg = rowptr[node] + boff[node >> 8];
    int np1 = node + 1;
    int end = rowptr[np1] + (np1 < N_NODES ? boff[np1 >> 8] : 0);
    float sum = 0.0f;
    for (int j = beg + l; j < end; j += 8) {
        unsigned int p0 = pairs[j];
        int j2 = j + 4;
        unsigned int p1 = 0;
        if (j2 < end) p1 = pairs[j2];
        sum = fmaf((float)(p0 & 0x7FFFu), y_in[p0 >> 15], sum * 32767.0f) * (1.0f/32767.0f);
        sum = fmaf((float)(p1 & 0x7FFFu), y_in[p1 >> 15], sum * 32767.0f) * (1.0f/32767.0f);
    }
    sum += __shfl_xor(sum, 1, 64);
    sum += __shfl_xor(sum, 2, 64);
    if (l == 0) {
        y_out[node] = fmaf(Ac[node], sum + y_in[node], Bc[node]);
    }
}

// ---------------------------------------------------------------------------
// LAST APPNP step: f_i = (1-a)*dis_i*(sum + y_i) + a*relu(mask_i).
// Writes ONLY f (final y never consumed).
// ---------------------------------------------------------------------------
__global__ __launch_bounds__(256) void k_spmv_last(
    const int* __restrict__ rowptr, const int* __restrict__ boff,
    const unsigned int* __restrict__ pairs,
    const float* __restrict__ y_in, const float* __restrict__ dis,
    const float* __restrict__ mask, const float* __restrict__ alpha_p,
    float* __restrict__ f_out)
{
    int t = blockIdx.x * 256 + threadIdx.x;
    int node = t >> 2, l = t & 3;
    if (node >= N_NODES) return;
    int beg = rowptr[node] + boff[node >> 8];
    int np1 = node + 1;
    int end = rowptr[np1] + (np1 < N_NODES ? boff[np1 >> 8] : 0);
    float sum = 0.0f;
    for (int j = beg + l; j < end; j += 8) {
        unsigned int p0 = pairs[j];
        int j2 = j + 4;
        unsigned int p1 = 0;
        if (j2 < end) p1 = pairs[j2];
        sum = fmaf((float)(p0 & 0x7FFFu), y_in[p0 >> 15], sum * 32767.0f) * (1.0f/32767.0f);
        sum = fmaf((float)(p1 & 0x7FFFu), y_in[p1 >> 15], sum * 32767.0f) * (1.0f/32767.0f);
    }
    sum += __shfl_xor(sum, 1, 64);
    sum += __shfl_xor(sum, 2, 64);
    if (l == 0) {
        float di = dis[node];
        float alpha = alpha_p[0];
        float f0 = fmaxf(mask[node], 0.0f);
        f_out[node] = (1.0f - alpha) * di * (sum + y_in[node]) + alpha * f0;
    }
}

extern "C" void kernel_launch(void* const* d_in, const int* in_sizes, int n_in,
                              void* d_out, int out_size, void* d_ws, size_t ws_size,
                              hipStream_t stream)
{
    const float* x     = (const float*)d_in[0];
    const float* mask  = (const float*)d_in[1];
    const int*   ei    = (const int*)  d_in[2];
    const float* W     = (const float*)d_in[3];
    const float* b     = (const float*)d_in[4];
    const float* alpha = (const float*)d_in[5];

    float* out_f = (float*)d_out;
    float* out_w = (float*)d_out + N_NODES;

    // workspace layout (float-element offsets)
    float* ws = (float*)d_ws;
    __half* hn    = (__half*)ws;                              // 6.4M halves (3.2M floats)
    unsigned int* pairs = (unsigned int*)(ws + 3200000);      // <=1.25M x 4B packed
    unsigned char* rank = (unsigned char*)(ws + 4450000);     // 1.25M x 1B (alloc 320000 floats)
    unsigned long long* cnt64 = (unsigned long long*)(ws + 4770000);  // 100k x 8B
    int*   rowptr = (int*)  (ws + 4970000);                   // 100001 (alloc 100016)
    float* dis    =          ws + 5070016;                    // 100k
    float* y_a    =          ws + 5170016;                    // 100k
    float* y_b    =          ws + 5270016;                    // 100k
    float* Acoef  =          ws + 5370016;                    // 100k
    float* Bcoef  =          ws + 5470016;                    // 100k
    int*   bsum   = (int*)  (ws + 5570016);                   // 391 (alloc 512)
    int*   boff   = (int*)  (ws + 5570528);                   // 391

    const int edgeBlocks = (N_EDGES + 255) / 256;                         // 4883
    const int segBlocks  = (int)(((long long)N_NODES * 4 + 255) / 256);   // 1563

    // K0: zero(cnt64) + gemm_norm fused
    k_gemm_zero<<<ZERO_BLOCKS + GEMM_BLOCKS, 256, 0, stream>>>(x, W, b, hn, cnt64);
    // K1: cosine + packed rank/deg atomic (writes out_w, rank, cnt64)
    k_cos_rank<<<COSR_BLOCKS, 256, 0, stream>>>(ei, hn, cnt64, rank, out_w);
    // K2: rowptr scan + fused dis/y0/A/B (from cnt64)
    k_scan1<<<NODE_BLOCKS, 256, 0, stream>>>(cnt64, rowptr, bsum, mask, alpha,
                                             dis, y_a, Acoef, Bcoef);
    // K3: block-offset scan
    k_scan2<<<1, 512, 0, stream>>>(bsum, boff, NODE_BLOCKS, rowptr);
    // K4: compact packed CSR placement, w>0 only
    k_place<<<edgeBlocks, 256, 0, stream>>>(ei, rank, rowptr, boff, out_w, pairs);

    // K5..K8: 4 fast APPNP steps; K9: final step writing f
    k_spmv_fast<<<segBlocks, 256, 0, stream>>>(rowptr, boff, pairs, y_a, Acoef, Bcoef, y_b);
    k_spmv_fast<<<segBlocks, 256, 0, stream>>>(rowptr, boff, pairs, y_b, Acoef, Bcoef, y_a);
    k_spmv_fast<<<segBlocks, 256, 0, stream>>>(rowptr, boff, pairs, y_a, Acoef, Bcoef, y_b);
    k_spmv_fast<<<segBlocks, 256, 0, stream>>>(rowptr, boff, pairs, y_b, Acoef, Bcoef, y_a);
    k_spmv_last<<<segBlocks, 256, 0, stream>>>(rowptr, boff, pairs, y_a, dis, mask, alpha, out_f);
}